// Round 9
// baseline (252.807 us; speedup 1.0000x reference)
//
#include <hip/hip_runtime.h>
#include <hip/hip_bf16.h>
#include <stdint.h>

typedef _Float16 half8 __attribute__((ext_vector_type(8)));
typedef _Float16 half4 __attribute__((ext_vector_type(4)));
typedef float    f32x4 __attribute__((ext_vector_type(4)));

#define MFMA16(a, b, c) __builtin_amdgcn_mfma_f32_16x16x32_f16(a, b, c, 0, 0, 0)

// global_load_lds helper: 16B per lane, LDS dest = wave-uniform base + lane*16.
typedef __attribute__((address_space(1))) const void GVOID;
typedef __attribute__((address_space(3))) void LVOID;
__device__ __forceinline__ void glds16(const void* g, void* l)
{
    __builtin_amdgcn_global_load_lds((GVOID*)g, (LVOID*)l, 16, 0, 0);
}

// raw barrier with compiler memory fences
#define BARRIER() do { asm volatile("" ::: "memory"); \
    __builtin_amdgcn_s_barrier(); \
    asm volatile("" ::: "memory"); } while (0)

// ---------------------------------------------------------------------------
// PREP: weight transposes + q/k fp16 convert + zero ctx.
// (R8 body, resubmitted after infra failure — attn zeroing lives in pmean's
// trivial blocks, which overlap working blocks.)
//   [0,2048)      WqT/WkT transpose
//   [2048,2112)   WvT transpose
//   [2112,2176)   WoT transpose
//   [2176,6272)   q/k fp32->fp16 convert
//   [6272,6528)   zero ctx (1 MB)
// ---------------------------------------------------------------------------
__global__ __launch_bounds__(256) void prep_all(
    const float* __restrict__ Wq, const float* __restrict__ Wk,
    const float* __restrict__ Wv, const float* __restrict__ Wo,
    const float* __restrict__ queries, const float* __restrict__ keys,
    _Float16* __restrict__ WqkT, _Float16* __restrict__ WvT,
    _Float16* __restrict__ WoT, _Float16* __restrict__ a16,
    float* __restrict__ ctx)
{
    __shared__ float t[32][33];
    const int id = blockIdx.x;
    const int tid = threadIdx.x;

    if (id < 2176) {
        const float* X; _Float16* Y; int R, C, bx, by;
        if (id < 2048) {
            const int isK = id >> 10;
            const int local = id & 1023;
            bx = local & 1;
            by = (local >> 1) & 31;
            const int hz = local >> 6;
            X = (isK ? Wk : Wq) + (long)hz * 65536;
            Y = WqkT + (long)isK * 1048576 + (long)hz * 65536;
            R = 1024; C = 64;
        } else if (id < 2112) {
            const int local = id - 2048;
            bx = local & 1; by = local >> 1;
            X = Wv; Y = WvT; R = 1024; C = 64;
        } else {
            const int local = id - 2112;
            bx = local & 31; by = local >> 5;
            X = Wo; Y = WoT; R = 64; C = 1024;
        }
        const int c0 = bx * 32, r0 = by * 32;
        const int tx = tid & 31, ty = tid >> 5;
#pragma unroll
        for (int i = 0; i < 4; ++i)
            t[ty + i * 8][tx] = X[(long)(r0 + ty + i * 8) * C + c0 + tx];
        __syncthreads();
#pragma unroll
        for (int i = 0; i < 4; ++i)
            Y[(long)(c0 + ty + i * 8) * R + r0 + tx] = (_Float16)t[tx][ty + i * 8];
    } else if (id < 6272) {
        const int isK = (id - 2176) >> 11;
        const int local = (id - 2176) & 2047;
        const float* S = isK ? keys : queries;
        _Float16* Dz = a16 + (long)isK * 4194304;
        const long i = ((long)local * 256 + tid) * 8;
        const float4 v0 = *(const float4*)(S + i);
        const float4 v1 = *(const float4*)(S + i + 4);
        half8 h;
        h[0] = (_Float16)v0.x; h[1] = (_Float16)v0.y;
        h[2] = (_Float16)v0.z; h[3] = (_Float16)v0.w;
        h[4] = (_Float16)v1.x; h[5] = (_Float16)v1.y;
        h[6] = (_Float16)v1.z; h[7] = (_Float16)v1.w;
        *(half8*)(Dz + i) = h;
    } else {
        const float4 z = {0.f, 0.f, 0.f, 0.f};
        ((float4*)ctx)[(long)(id - 6272) * 256 + tid] = z;
    }
}

// ---------------------------------------------------------------------------
// Fused launch: blocks [0,32) = v-projection (pad 72->68, fits 34 KB);
// blocks [32,544) = q+k projection, SINGLE-buffer 32 KB + 2-barrier loop
// (m97 shape). R5 proved dbuf+counted-vmcnt == plain syncthreads here, so
// the 64 KB dbuf only cost occupancy: halving LDS doubles blocks/CU (2->4),
// and m114-style inter-block wave overlap does the pipelining.
// ---------------------------------------------------------------------------
__global__ __launch_bounds__(256, 4) void qk_vproj(
    const _Float16* __restrict__ A16,   // [2][4096][1024] fp16 (q16|k16)
    const _Float16* __restrict__ BT,    // [2][1024][1024] fp16 (WqT|WkT)
    const float* __restrict__ bias0, const float* __restrict__ bias1,
    _Float16* __restrict__ Cout,        // [2][4096][1024] fp16 (qall|kall)
    const float* __restrict__ values,   // [4096][1024] fp32
    const _Float16* __restrict__ WvT,   // [64][1024] fp16
    const float* __restrict__ bv,       // [64]
    _Float16* __restrict__ vT)          // [4][64][1024] fp16
{
    __shared__ __align__(16) char smem[34816];
    const int lid = blockIdx.x;
    const int tid = threadIdx.x;
    const int wave = tid >> 6, lane = tid & 63;
    const int m16  = lane & 15, quad = lane >> 4;

    if (lid < 32) {
        // ================= v-projection role =================
        _Float16 (*As)[68] = (_Float16(*)[68])smem;            // 128x68
        _Float16 (*Bs)[68] = (_Float16(*)[68])(smem + 17408);  // 128x68
        const int m0 = lid * 128;

        const int acol = (tid & 15) * 4;
        const int arb  = tid >> 4;
        const int bj   = tid >> 1;
        const int bcc  = (tid & 1) * 32;
        const int jn = (bj > 63) ? 63 : bj;     // N=64 clamp
        const _Float16* bpB = WvT + (long)jn * 1024;

        f32x4 acc[2][4];
        {
            f32x4 zz = {0.f, 0.f, 0.f, 0.f};
#pragma unroll
            for (int i = 0; i < 2; ++i)
#pragma unroll
                for (int j = 0; j < 4; ++j) acc[i][j] = zz;
        }

        for (int k0 = 0; k0 < 1024; k0 += 64) {
            {
                float4 av[8];
#pragma unroll
                for (int p = 0; p < 8; ++p)
                    av[p] = *(const float4*)(values + (long)(m0 + arb + p * 16) * 1024 + k0 + acol);
#pragma unroll
                for (int p = 0; p < 8; ++p) {
                    half4 hv;
                    hv[0] = (_Float16)av[p].x; hv[1] = (_Float16)av[p].y;
                    hv[2] = (_Float16)av[p].z; hv[3] = (_Float16)av[p].w;
                    *(half4*)&As[arb + p * 16][acol] = hv;
                }
            }
            {
                const _Float16* bp = bpB + k0 + bcc;
                half8 b0 = *(const half8*)(bp);
                half8 b1 = *(const half8*)(bp + 8);
                half8 b2 = *(const half8*)(bp + 16);
                half8 b3 = *(const half8*)(bp + 24);
                *(half8*)&Bs[bj][bcc]      = b0;
                *(half8*)&Bs[bj][bcc + 8]  = b1;
                *(half8*)&Bs[bj][bcc + 16] = b2;
                *(half8*)&Bs[bj][bcc + 24] = b3;
            }
            __syncthreads();
#pragma unroll
            for (int kss = 0; kss < 2; ++kss) {
                const int ko = kss * 32 + quad * 8;
                const half8 a0 = *(const half8*)&As[wave * 32 + m16][ko];
                const half8 a1 = *(const half8*)&As[wave * 32 + 16 + m16][ko];
#pragma unroll
                for (int c = 0; c < 4; ++c) {
                    const half8 bf = *(const half8*)&Bs[c * 16 + m16][ko];
                    acc[0][c] = MFMA16(a0, bf, acc[0][c]);
                    acc[1][c] = MFMA16(a1, bf, acc[1][c]);
                }
            }
            __syncthreads();
        }

        // epilogue: vT[b][e][t] = (fp16)(acc + bv[e])
#pragma unroll
        for (int hh = 0; hh < 2; ++hh) {
#pragma unroll
            for (int c = 0; c < 4; ++c) {
                const int e  = c * 16 + m16;
                const float bb = bv[e];
#pragma unroll
                for (int r = 0; r < 4; ++r) {
                    const int row = m0 + wave * 32 + hh * 16 + quad * 4 + r;
                    const int b = row >> 10, tt = row & 1023;
                    vT[(long)b * 65536 + (long)e * 1024 + tt] =
                        (_Float16)(acc[hh][c][r] + bb);
                }
            }
        }
        return;
    }

    // ================= q+k projection role (single-buffer) =================
    const int lid2 = lid - 32;            // 0..511
    const int xcd = lid2 & 7, loc = lid2 >> 3;
    const int sw  = xcd * 64 + loc;       // bijective (512 % 8 == 0)
    const int nt  = sw & 7;
    const int tm2 = sw >> 3;
    const int mt  = tm2 & 31;
    const int z   = tm2 >> 5;             // 0 = q, 1 = k

    const int n0 = nt * 128;
    const int m0 = mt * 128;

    const char* Az = (const char*)(A16 + (long)z * 4194304);
    const char* Bz = (const char*)(BT  + (long)z * 1048576);

    const int colbyte = (((lane & 7) ^ (lane >> 3)) << 4);
    const char* gaBase = Az + ((long)(m0 + wave * 32 + (lane >> 3)) << 11) + colbyte;
    const char* gbBase = Bz + ((long)(n0 + wave * 32 + (lane >> 3)) << 11) + colbyte;

    f32x4 acc[2][8];
    {
        f32x4 zz = {0.f, 0.f, 0.f, 0.f};
#pragma unroll
        for (int i = 0; i < 2; ++i)
#pragma unroll
            for (int j = 0; j < 8; ++j) acc[i][j] = zz;
    }

    _Float16* As = (_Float16*)smem;            // [128][64] linear
    _Float16* Bs = (_Float16*)(smem + 16384);  // [128][64] linear

    for (int t = 0; t < 16; ++t) {
        const int k0 = t * 64;
        {
            const char* ga = gaBase + (k0 << 1);
            const char* gb = gbBase + (k0 << 1);
            _Float16* la = As + wave * 32 * 64;
            _Float16* lb = Bs + wave * 32 * 64;
#pragma unroll
            for (int i = 0; i < 4; ++i) {
                glds16(ga + (long)i * 8 * 2048, la + i * 8 * 64);
                glds16(gb + (long)i * 8 * 2048, lb + i * 8 * 64);
            }
        }
        __syncthreads();               // drains glds (vmcnt 0) + barrier
        {
            const char* Ab = (const char*)As;
            const char* Bp = (const char*)Bs;
            const int sw4 = (m16 & 7) << 4;
#pragma unroll
            for (int kss = 0; kss < 2; ++kss) {
                const int kbs = (kss * 64 + quad * 16) ^ sw4;
                const half8 a0 = *(const half8*)(Ab + (wave * 32 + m16) * 128 + kbs);
                const half8 a1 = *(const half8*)(Ab + (wave * 32 + 16 + m16) * 128 + kbs);
#pragma unroll
                for (int c = 0; c < 8; ++c) {
                    const half8 bfr = *(const half8*)(Bp + (c * 16 + m16) * 128 + kbs);
                    acc[0][c] = MFMA16(a0, bfr, acc[0][c]);
                    acc[1][c] = MFMA16(a1, bfr, acc[1][c]);
                }
            }
        }
        __syncthreads();               // all waves done reading; safe restage
    }

    const float* bias = z ? bias1 : bias0;
    _Float16* Cz = Cout + (long)z * 4194304;
#pragma unroll
    for (int hh = 0; hh < 2; ++hh) {
#pragma unroll
        for (int c = 0; c < 8; ++c) {
            const int col = n0 + c * 16 + m16;
            const float bb = bias[col];
#pragma unroll
            for (int r = 0; r < 4; ++r) {
                const int row = m0 + wave * 32 + hh * 16 + quad * 4 + r;
                Cz[(long)row * 1024 + col] = (_Float16)(acc[hh][c][r] + bb);
            }
        }
    }
}

// ---------------------------------------------------------------------------
// MFMA GEMM (fp32 A path) — out-projection only.
// ---------------------------------------------------------------------------
__global__ __launch_bounds__(256, 2) void gemm_f16_v2(
    const float* __restrict__ A0, const float* __restrict__ A1,
    const _Float16* __restrict__ BT,
    const float* __restrict__ bias0, const float* __restrict__ bias1,
    void* __restrict__ Cout,
    int N, int lda, int ldbt, int ldc,
    long aBS, long bBS, long cBS,
    int c_half, int atomic, int nks, int kchunk)
{
    __shared__ __align__(16) _Float16 As[128][72];
    __shared__ __align__(16) _Float16 Bs[128][72];

    const int gx  = gridDim.x, gy = gridDim.y;
    const int nwg = gx * gy * (int)gridDim.z;
    const int lid = (int)blockIdx.x + gx * ((int)blockIdx.y + gy * (int)blockIdx.z);
    const int q8  = nwg >> 3, r8 = nwg & 7;
    const int xcd = lid & 7, loc = lid >> 3;
    const int sw  = (xcd < r8 ? xcd * (q8 + 1) : r8 * (q8 + 1) + (xcd - r8) * q8) + loc;
    const int nt  = sw % gx;
    const int tm2 = sw / gx;
    const int mt  = tm2 % gy;
    const int bz  = tm2 / gy;

    const int b = bz / nks, ks = bz % nks;
    const int kbeg = ks * kchunk;
    const int kend = kbeg + kchunk;

    const float* A = A1 ? (b ? A1 : A0) : (A0 + (long)b * aBS);
    const _Float16* Bb = BT + (long)b * bBS;

    const int n0 = nt * 128;
    const int m0 = mt * 128;
    const int tid  = threadIdx.x;
    const int wave = tid >> 6, lane = tid & 63;
    const int m16  = lane & 15, quad = lane >> 4;

    const int acol = (tid & 15) * 4;
    const int arb  = tid >> 4;
    const int bj   = tid >> 1;
    const int bcc  = (tid & 1) * 32;
    int jn = n0 + bj; if (jn > N - 1) jn = N - 1;
    const _Float16* bpB = Bb + (long)jn * ldbt;

    f32x4 acc[2][8];
    {
        f32x4 zz = {0.f, 0.f, 0.f, 0.f};
#pragma unroll
        for (int i = 0; i < 2; ++i)
#pragma unroll
            for (int j = 0; j < 8; ++j) acc[i][j] = zz;
    }

    for (int k0 = kbeg; k0 < kend; k0 += 64) {
        {
            float4 av[8];
#pragma unroll
            for (int p = 0; p < 8; ++p)
                av[p] = *(const float4*)(A + (long)(m0 + arb + p * 16) * lda + k0 + acol);
#pragma unroll
            for (int p = 0; p < 8; ++p) {
                half4 hv;
                hv[0] = (_Float16)av[p].x; hv[1] = (_Float16)av[p].y;
                hv[2] = (_Float16)av[p].z; hv[3] = (_Float16)av[p].w;
                *(half4*)&As[arb + p * 16][acol] = hv;
            }
        }
        {
            const _Float16* bp = bpB + k0 + bcc;
            half8 b0 = *(const half8*)(bp);
            half8 b1 = *(const half8*)(bp + 8);
            half8 b2 = *(const half8*)(bp + 16);
            half8 b3 = *(const half8*)(bp + 24);
            *(half8*)&Bs[bj][bcc]      = b0;
            *(half8*)&Bs[bj][bcc + 8]  = b1;
            *(half8*)&Bs[bj][bcc + 16] = b2;
            *(half8*)&Bs[bj][bcc + 24] = b3;
        }
        __syncthreads();
#pragma unroll
        for (int kss = 0; kss < 2; ++kss) {
            const int ko = kss * 32 + quad * 8;
            const half8 a0 = *(const half8*)&As[wave * 32 + m16][ko];
            const half8 a1 = *(const half8*)&As[wave * 32 + 16 + m16][ko];
#pragma unroll
            for (int c = 0; c < 8; ++c) {
                const half8 bf = *(const half8*)&Bs[c * 16 + m16][ko];
                acc[0][c] = MFMA16(a0, bf, acc[0][c]);
                acc[1][c] = MFMA16(a1, bf, acc[1][c]);
            }
        }
        __syncthreads();
    }

    const float* bias = b ? bias1 : bias0;
    const int addb = (bias != nullptr) && (kbeg == 0);
#pragma unroll
    for (int hh = 0; hh < 2; ++hh) {
#pragma unroll
        for (int c = 0; c < 8; ++c) {
            const int col = n0 + c * 16 + m16;
            if (col >= N) continue;
            const float bb = addb ? bias[col] : 0.f;
#pragma unroll
            for (int r = 0; r < 4; ++r) {
                const int row = m0 + wave * 32 + hh * 16 + quad * 4 + r;
                const float v = acc[hh][c][r] + bb;
                const long idx = (long)b * cBS + (long)row * ldc + col;
                if (atomic)      atomicAdd(&((float*)Cout)[idx], v);
                else if (c_half) ((_Float16*)Cout)[idx] = (_Float16)v;
                else             ((float*)Cout)[idx] = v;
            }
        }
    }
}

// ---------------------------------------------------------------------------
// Pass 1: per (b,h,s) row stats, KVBLK=128 (R6/R7-passing, unchanged).
// ---------------------------------------------------------------------------
__global__ __launch_bounds__(256, 4) void attn_stats(
    const _Float16* __restrict__ q_all, const _Float16* __restrict__ k_all,
    float* __restrict__ m_out, float* __restrict__ il_out)
{
    const int st = blockIdx.x, h = blockIdx.y, b = blockIdx.z;
    const int tid = threadIdx.x, wave = tid >> 6, lane = tid & 63;
    const int m16 = lane & 15, quad = lane >> 4;
    const int s0 = st * 64;
    const int sw = s0 + wave * 16;

    __shared__ __align__(16) _Float16 qs[64][72];
    __shared__ __align__(16) _Float16 ks[128][72];

    const int srow = tid >> 2;
    const int scol = (tid & 3) * 16;

    {
        const _Float16* qsrc = q_all + ((long)(b * 1024 + s0 + srow)) * 1024 + h * 64 + scol;
        *(half8*)&qs[srow][scol]     = *(const half8*)(qsrc);
        *(half8*)&qs[srow][scol + 8] = *(const half8*)(qsrc + 8);
    }

    const _Float16* ksrcb = k_all + ((long)(b * 1024 + srow)) * 1024 + h * 64 + scol;

    float mr[4], lr[4];
#pragma unroll
    for (int r = 0; r < 4; ++r) { mr[r] = -3.0e38f; lr[r] = 0.f; }

    half8 a0, a1;
    for (int ch = 0; 2 * ch <= st; ++ch) {
        const int tbase = 2 * ch;
        const int two = (tbase + 1 <= st);

        const _Float16* ksrc0 = ksrcb + (long)(tbase * 64) * 1024;
        const half8 k0 = *(const half8*)(ksrc0);
        const half8 k1 = *(const half8*)(ksrc0 + 8);
        half8 k2, k3;
        if (two) {
            const _Float16* ksrc1 = ksrc0 + (long)64 * 1024;
            k2 = *(const half8*)(ksrc1);
            k3 = *(const half8*)(ksrc1 + 8);
        }

        __syncthreads();
        *(half8*)&ks[srow][scol]     = k0;
        *(half8*)&ks[srow][scol + 8] = k1;
        if (two) {
            *(half8*)&ks[64 + srow][scol]     = k2;
            *(half8*)&ks[64 + srow][scol + 8] = k3;
        }
        __syncthreads();

        if (ch == 0) {
            a0 = *(const half8*)&qs[wave * 16 + m16][quad * 8];
            a1 = *(const half8*)&qs[wave * 16 + m16][quad * 8 + 32];
        }

        const int ncol = two ? 8 : 4;
        for (int c = 0; c < ncol; ++c) {
            const half8 b0 = *(const half8*)&ks[c * 16 + m16][quad * 8];
            const half8 b1 = *(const half8*)&ks[c * 16 + m16][quad * 8 + 32];
            f32x4 cc = {0.f, 0.f, 0.f, 0.f};
            cc = MFMA16(a0, b0, cc);
            cc = MFMA16(a1, b1, cc);
            const int tile = tbase + (c >> 2);
            if (tile < st) {
#pragma unroll
                for (int r = 0; r < 4; ++r) {
                    const float zz = cc[r] * 0.125f;
                    const float nm = fmaxf(mr[r], zz);
                    lr[r] = lr[r] * __expf(mr[r] - nm) + __expf(zz - nm);
                    mr[r] = nm;
                }
            } else {
                const int col = tile * 64 + (c & 3) * 16 + m16;
#pragma unroll
                for (int r = 0; r < 4; ++r) {
                    const int row = sw + quad * 4 + r;
                    if (col <= row) {
                        const float zz = cc[r] * 0.125f;
                        const float nm = fmaxf(mr[r], zz);
                        lr[r] = lr[r] * __expf(mr[r] - nm) + __expf(zz - nm);
                        mr[r] = nm;
                    }
                }
            }
        }
    }

#pragma unroll
    for (int mk = 1; mk < 16; mk <<= 1) {
#pragma unroll
        for (int r = 0; r < 4; ++r) {
            const float om = __shfl_xor(mr[r], mk);
            const float ol = __shfl_xor(lr[r], mk);
            const float nm = fmaxf(mr[r], om);
            lr[r] = lr[r] * __expf(mr[r] - nm) + ol * __expf(om - nm);
            mr[r] = nm;
        }
    }
    if (m16 == 0) {
#pragma unroll
        for (int r = 0; r < 4; ++r) {
            const long idx = ((long)(b * 16 + h)) * 1024 + sw + quad * 4 + r;
            m_out[idx]  = mr[r];
            il_out[idx] = 1.f / lr[r];
        }
    }
}

// ---------------------------------------------------------------------------
// Pass 2: head-mean softmax + fused PV. Trivial blocks write the attn
// upper-triangle zeros (overlap working blocks -> free).
// ---------------------------------------------------------------------------
__global__ __launch_bounds__(256, 4) void attn_pmean(
    const _Float16* __restrict__ q_all, const _Float16* __restrict__ k_all,
    const float* __restrict__ m_in, const float* __restrict__ il_in,
    const _Float16* __restrict__ vT,
    float* __restrict__ attn,
    float* __restrict__ ctx)
{
    const int ttile = blockIdx.x, stile = blockIdx.y, b = blockIdx.z;
    const int tid = threadIdx.x;
    if (ttile > stile) {
        const int c4 = (tid & 15) * 4;
        float4 zz = {0.f, 0.f, 0.f, 0.f};
#pragma unroll
        for (int i = 0; i < 4; ++i) {
            const int r = stile * 64 + (tid >> 4) + i * 16;
            *(float4*)&attn[((long)(b * 1024 + r)) * 1024 + ttile * 64 + c4] = zz;
        }
        return;
    }

    __shared__ __align__(16) _Float16 qs2[2][64 * 64];
    __shared__ __align__(16) _Float16 ks2[2][64 * 64];
    __shared__ __align__(16) float mls[16][64];
    __shared__ __align__(16) float ils[16][64];

    const int wave = tid >> 6, lane = tid & 63;
    const int m16 = lane & 15, quad = lane >> 4;
    const int s0 = stile * 64;
    const int t0 = ttile * 64;
    const int sw = s0 + wave * 16;
    const int diag = (ttile == stile);

    {
        const int hh = tid >> 4;
        const int c4 = (tid & 15) * 4;
        const long ix = ((long)(b * 16 + hh)) * 1024 + s0 + c4;
        const float4 mv4 = *(const float4*)&m_in[ix];
        const float4 iv4 = *(const float4*)&il_in[ix];
        *(float4*)&mls[hh][c4] = mv4;
        *(float4*)&ils[hh][c4] = iv4;
    }

    const int colb = (((lane & 7) ^ (lane >> 3)) << 4);
    const char* gq = (const char*)q_all + ((long)(b * 1024 + s0 + wave * 16 + (lane >> 3)) << 11) + colb;
    const char* gk = (const char*)k_all + ((long)(b * 1024 + t0 + wave * 16 + (lane >> 3)) << 11) + colb;

    auto STAGE_P = [&](int bf, int h) {
        const char* q = gq + h * 128;
        const char* k = gk + h * 128;
        _Float16* lq = &qs2[bf][wave * 16 * 64];
        _Float16* lk = &ks2[bf][wave * 16 * 64];
        glds16(q, lq);
        glds16(q + 8 * 2048, lq + 8 * 64);
        glds16(k, lk);
        glds16(k + 8 * 2048, lk + 8 * 64);
    };

    STAGE_P(0, 0);
    STAGE_P(1, 1);
    asm volatile("s_waitcnt lgkmcnt(0)" ::: "memory");
    BARRIER();

    float pm[4][4];
#pragma unroll
    for (int c = 0; c < 4; ++c)
#pragma unroll
        for (int r = 0; r < 4; ++r) pm[c][r] = 0.f;

    const int swz = (m16 & 7) << 4;
    int cur = 0;

    auto COMPUTE_H = [&](int h, int bf) {
        const char* Qc = (const char*)&qs2[bf][0];
        const char* Kc = (const char*)&ks2[bf][0];
        const half8 a0 = *(const half8*)(Qc + (wave * 16 + m16) * 128 + ((quad * 16) ^ swz));
        const half8 a1 = *(const half8*)(Qc + (wave * 16 + m16) * 128 + ((quad * 16 + 64) ^ swz));
        const float4 mv = *(const float4*)&mls[h][wave * 16 + quad * 4];
        const float4 iv = *(const float4*)&ils[h][wave * 16 + quad * 4];
        const float mrow[4] = {mv.x, mv.y, mv.z, mv.w};
        const float irow[4] = {iv.x, iv.y, iv.z, iv.w};
        if (!diag) {
#pragma unroll
            for (int c = 0; c < 4; ++c) {
                const half8 b0 = *(const half8*)(Kc + (c * 16 + m16) * 128 + ((quad * 16) ^ swz));
                const half8 b1 = *(const half8*)(Kc + (c * 16 + m16) * 128 + ((quad * 16 + 64) ^ swz));
                f32x4 cc = {0.f, 0.f, 0.f, 0.f};
                cc = MFMA16(a0, b0, cc);
                cc = MFMA16(a1, b1, cc);
#pragma unroll
                for (int r = 0; r < 4; ++r)
                    pm[c][r] += __expf(cc[r] * 0.125f - mrow[r]) * irow[r];
            }
        } else {
#pragma unroll
            for (int c = 0; c < 4; ++c) {
                const half8 b0 = *(const half8*)(Kc + (c * 16 + m16) * 128 + ((quad * 16) ^ swz));
                const half8 b1 = *(const half8*)(Kc + (c * 16 + m16) * 128 + ((quad * 16 + 64) ^ swz));
                f32x4 cc = {0.f, 0.f, 0.f, 0.f};
                cc = MFMA16(a0, b0, cc);
                cc = MFMA16(a1, b1, cc);
                const int col = t0 + c * 16 + m16;
#pragma unroll
                for (int r = 0; r < 4; ++r) {
                    const int row = sw + quad * 4 + r;
                    if (col <= row)
                        pm[c][r] += __expf(cc[r] * 0.125f - mrow[r]) * irow[r];
                }
            }
        }
    };

    for (int h = 0; h < 15; ++h) {
        asm volatile("s_waitcnt vmcnt(4)" ::: "memory");
        __builtin_amdgcn_sched_barrier(0);
        BARRIER();
        COMPUTE_H(h, cur);
        BARRIER();
        if (h < 14) STAGE_P(cur, h + 2);
        cur ^= 1;
    }
    asm volatile("s_waitcnt vmcnt(0)" ::: "memory");
    __builtin_amdgcn_sched_barrier(0);
    BARRIER();
    COMPUTE_H(15, cur);
    __syncthreads();   // all waves done reading LDS; qs2[0] reusable for P

    // attn write + P stash into qs2[0], chunk-XOR swizzled
    {
        char* Pb = (char*)&qs2[0][0];
#pragma unroll
        for (int c = 0; c < 4; ++c) {
#pragma unroll
            for (int r = 0; r < 4; ++r) {
                const int rloc = (wave << 4) + (quad << 2) + r;
                const int cloc = c * 16 + m16;
                const float p = pm[c][r] * 0.0625f;
                attn[((long)(b * 1024 + s0 + rloc)) * 1024 + t0 + cloc] = p;
                const int chunk = (cloc >> 3) ^ (rloc & 7);
                *(_Float16*)(Pb + rloc * 128 + (chunk << 4) + (cloc & 7) * 2) =
                    (_Float16)p;
            }
        }
    }
    __syncthreads();

    // PV: ctx[s][e] += sum_t P[s][t] * vT[e][t]
    const _Float16* vTb = vT + (long)b * 65536 + t0;
    const char* Pb = (const char*)&qs2[0][0];
    const int Rr = wave * 16 + m16;
    f32x4 apv[4];
    {
        f32x4 zz = {0.f, 0.f, 0.f, 0.f};
#pragma unroll
        for (int c = 0; c < 4; ++c) apv[c] = zz;
    }
#pragma unroll
    for (int kss = 0; kss < 2; ++kss) {
        const int chunk = (kss * 4 + quad) ^ (Rr & 7);
        const half8 a = *(const half8*)(Pb + Rr * 128 + (chunk << 4));
#pragma unroll
        for (int c = 0; c < 4; ++c) {
            const half8 bf = *(const half8*)(vTb + (long)(c * 16 + m16) * 1024 + kss * 32 + quad * 8);
            apv[c] = MFMA16(a, bf, apv[c]);
        }
    }
#pragma unroll
    for (int c = 0; c < 4; ++c) {
#pragma unroll
        for (int r = 0; r < 4; ++r) {
            const int row = sw + quad * 4 + r;
            const int e   = c * 16 + m16;
            atomicAdd(&ctx[((long)(b * 1024 + row)) * 64 + e], apv[c][r]);
        }
    }
}

// ---------------------------------------------------------------------------
extern "C" void kernel_launch(void* const* d_in, const int* in_sizes, int n_in,
                              void* d_out, int out_size, void* d_ws, size_t ws_size,
                              hipStream_t stream)
{
    const float* queries = (const float*)d_in[0];
    const float* keys    = (const float*)d_in[1];
    const float* values  = (const float*)d_in[2];
    const float* Wq = (const float*)d_in[4];
    const float* bq = (const float*)d_in[5];
    const float* Wk = (const float*)d_in[6];
    const float* bk = (const float*)d_in[7];
    const float* Wv = (const float*)d_in[8];
    const float* bv = (const float*)d_in[9];
    const float* Wo = (const float*)d_in[10];
    const float* bo = (const float*)d_in[11];

    float* out_ptr  = (float*)d_out;                   // [4096][1024]
    float* attn_ptr = out_ptr + (long)4096 * 1024;     // [4][1024][1024]

    uint8_t* w = (uint8_t*)d_ws;
    size_t off = 0;
    auto alloc = [&](size_t bytes) {
        void* p = w + off;
        off = (off + bytes + 255) & ~(size_t)255;
        return p;
    };
    _Float16* WqkT  = (_Float16*)alloc((size_t)2 * 1024 * 1024 * 2); // WqT|WkT
    _Float16* WvT   = (_Float16*)alloc((size_t)64 * 1024 * 2);       // [e][d]
    _Float16* WoT   = (_Float16*)alloc((size_t)1024 * 64 * 2);       // [d][e]
    _Float16* qkall = (_Float16*)alloc((size_t)2 * 4194304 * 2);     // qall|kall
    _Float16* a16   = (_Float16*)alloc((size_t)2 * 4194304 * 2);     // q16|k16
    _Float16* vT    = (_Float16*)alloc((size_t)4 * 64 * 1024 * 2);   // per-b [e][t]
    float*    ctx   = (float*)alloc((size_t)4096 * 64 * 4);
    float*    mbuf  = (float*)alloc((size_t)65536 * 4);
    float*    ilbuf = (float*)alloc((size_t)65536 * 4);
    (void)ws_size; (void)in_sizes; (void)n_in; (void)out_size;

    _Float16* qall = qkall;
    _Float16* kall = qkall + (long)4194304;

    // 1. prep: transposes + cvt + zero ctx
    prep_all<<<dim3(6528, 1, 1), 256, 0, stream>>>(
        Wq, Wk, Wv, Wo, queries, keys,
        WqkT, WvT, WoT, a16, ctx);

    // 2. fused q+k projection (512 blocks, 4/CU) + v projection -> vT (32)
    qk_vproj<<<dim3(544, 1, 1), 256, 0, stream>>>(
        a16, WqkT, bq, bk, qkall, values, WvT, bv, vT);

    // 3. softmax stats (KVBLK=128)
    attn_stats<<<dim3(16, 16, 4), 256, 0, stream>>>(qall, kall, mbuf, ilbuf);

    // 4. head-mean probabilities + fused PV into ctx (+ upper-tri zeros)
    attn_pmean<<<dim3(16, 16, 4), 256, 0, stream>>>(qall, kall, mbuf, ilbuf, vT, attn_ptr, ctx);

    // 5. out = ctx @ Wo + bo
    gemm_f16_v2<<<dim3(8, 32, 1), 256, 0, stream>>>(
        ctx, nullptr, WoT, bo, nullptr, out_ptr,
        1024, 64, 64, 1024,
        0, 0, 0,
        /*c_half=*/0, /*atomic=*/0, /*nks=*/1, /*kchunk=*/64);
}

// Round 10
// 225.401 us; speedup vs baseline: 1.1216x; 1.1216x over previous
//
#include <hip/hip_runtime.h>
#include <hip/hip_bf16.h>
#include <stdint.h>

typedef _Float16 half8 __attribute__((ext_vector_type(8)));
typedef _Float16 half4 __attribute__((ext_vector_type(4)));
typedef float    f32x4 __attribute__((ext_vector_type(4)));

#define MFMA16(a, b, c) __builtin_amdgcn_mfma_f32_16x16x32_f16(a, b, c, 0, 0, 0)

// global_load_lds helper: 16B per lane, LDS dest = wave-uniform base + lane*16.
typedef __attribute__((address_space(1))) const void GVOID;
typedef __attribute__((address_space(3))) void LVOID;
__device__ __forceinline__ void glds16(const void* g, void* l)
{
    __builtin_amdgcn_global_load_lds((GVOID*)g, (LVOID*)l, 16, 0, 0);
}

// raw barrier with compiler memory fences
#define BARRIER() do { asm volatile("" ::: "memory"); \
    __builtin_amdgcn_s_barrier(); \
    asm volatile("" ::: "memory"); } while (0)

// ---------------------------------------------------------------------------
// PREP: weight transposes + q/k fp16 convert + zero ctx.
// (attn zeroing lives in pmean's trivial blocks, which overlap working blocks)
//   [0,2048)      WqT/WkT transpose
//   [2048,2112)   WvT transpose
//   [2112,2176)   WoT transpose
//   [2176,6272)   q/k fp32->fp16 convert
//   [6272,6528)   zero ctx (1 MB)
// ---------------------------------------------------------------------------
__global__ __launch_bounds__(256) void prep_all(
    const float* __restrict__ Wq, const float* __restrict__ Wk,
    const float* __restrict__ Wv, const float* __restrict__ Wo,
    const float* __restrict__ queries, const float* __restrict__ keys,
    _Float16* __restrict__ WqkT, _Float16* __restrict__ WvT,
    _Float16* __restrict__ WoT, _Float16* __restrict__ a16,
    float* __restrict__ ctx)
{
    __shared__ float t[32][33];
    const int id = blockIdx.x;
    const int tid = threadIdx.x;

    if (id < 2176) {
        const float* X; _Float16* Y; int R, C, bx, by;
        if (id < 2048) {
            const int isK = id >> 10;
            const int local = id & 1023;
            bx = local & 1;
            by = (local >> 1) & 31;
            const int hz = local >> 6;
            X = (isK ? Wk : Wq) + (long)hz * 65536;
            Y = WqkT + (long)isK * 1048576 + (long)hz * 65536;
            R = 1024; C = 64;
        } else if (id < 2112) {
            const int local = id - 2048;
            bx = local & 1; by = local >> 1;
            X = Wv; Y = WvT; R = 1024; C = 64;
        } else {
            const int local = id - 2112;
            bx = local & 31; by = local >> 5;
            X = Wo; Y = WoT; R = 64; C = 1024;
        }
        const int c0 = bx * 32, r0 = by * 32;
        const int tx = tid & 31, ty = tid >> 5;
#pragma unroll
        for (int i = 0; i < 4; ++i)
            t[ty + i * 8][tx] = X[(long)(r0 + ty + i * 8) * C + c0 + tx];
        __syncthreads();
#pragma unroll
        for (int i = 0; i < 4; ++i)
            Y[(long)(c0 + ty + i * 8) * R + r0 + tx] = (_Float16)t[tx][ty + i * 8];
    } else if (id < 6272) {
        const int isK = (id - 2176) >> 11;
        const int local = (id - 2176) & 2047;
        const float* S = isK ? keys : queries;
        _Float16* Dz = a16 + (long)isK * 4194304;
        const long i = ((long)local * 256 + tid) * 8;
        const float4 v0 = *(const float4*)(S + i);
        const float4 v1 = *(const float4*)(S + i + 4);
        half8 h;
        h[0] = (_Float16)v0.x; h[1] = (_Float16)v0.y;
        h[2] = (_Float16)v0.z; h[3] = (_Float16)v0.w;
        h[4] = (_Float16)v1.x; h[5] = (_Float16)v1.y;
        h[6] = (_Float16)v1.z; h[7] = (_Float16)v1.w;
        *(half8*)(Dz + i) = h;
    } else {
        const float4 z = {0.f, 0.f, 0.f, 0.f};
        ((float4*)ctx)[(long)(id - 6272) * 256 + tid] = z;
    }
}

// ---------------------------------------------------------------------------
// R10: qk role REVERTED to the R7 double-buffered counted-vmcnt body.
// R9 counters falsified R8's single-buffer theory: grid is 544 blocks on
// 256 CUs = 2.1 blocks/CU, so the LDS-occupancy cap was never binding, and
// the dbuf's intra-block overlap (stage t+1 in flight across tile t's
// compute) was worth ~2x (70.5 -> ~37-40 us). Blocks [0,32) = v-projection
// writing vT transposed fp16; blocks [32,544) = q+k projection.
// ---------------------------------------------------------------------------
__global__ __launch_bounds__(256, 2) void qk_vproj(
    const _Float16* __restrict__ A16,   // [2][4096][1024] fp16 (q16|k16)
    const _Float16* __restrict__ BT,    // [2][1024][1024] fp16 (WqT|WkT)
    const float* __restrict__ bias0, const float* __restrict__ bias1,
    _Float16* __restrict__ Cout,        // [2][4096][1024] fp16 (qall|kall)
    const float* __restrict__ values,   // [4096][1024] fp32
    const _Float16* __restrict__ WvT,   // [64][1024] fp16
    const float* __restrict__ bv,       // [64]
    _Float16* __restrict__ vT)          // [4][64][1024] fp16
{
    __shared__ __align__(16) char smem[65536];
    const int lid = blockIdx.x;
    const int tid = threadIdx.x;
    const int wave = tid >> 6, lane = tid & 63;
    const int m16  = lane & 15, quad = lane >> 4;

    if (lid < 32) {
        // ================= v-projection role =================
        _Float16 (*As)[72] = (_Float16(*)[72])smem;                  // 128x72
        _Float16 (*Bs)[72] = (_Float16(*)[72])(smem + 128 * 72 * 2); // 128x72
        const int m0 = lid * 128;

        const int acol = (tid & 15) * 4;
        const int arb  = tid >> 4;
        const int bj   = tid >> 1;
        const int bcc  = (tid & 1) * 32;
        const int jn = (bj > 63) ? 63 : bj;     // N=64 clamp
        const _Float16* bpB = WvT + (long)jn * 1024;

        f32x4 acc[2][4];
        {
            f32x4 zz = {0.f, 0.f, 0.f, 0.f};
#pragma unroll
            for (int i = 0; i < 2; ++i)
#pragma unroll
                for (int j = 0; j < 4; ++j) acc[i][j] = zz;
        }

        for (int k0 = 0; k0 < 1024; k0 += 64) {
            {
                float4 av[8];
#pragma unroll
                for (int p = 0; p < 8; ++p)
                    av[p] = *(const float4*)(values + (long)(m0 + arb + p * 16) * 1024 + k0 + acol);
#pragma unroll
                for (int p = 0; p < 8; ++p) {
                    half4 hv;
                    hv[0] = (_Float16)av[p].x; hv[1] = (_Float16)av[p].y;
                    hv[2] = (_Float16)av[p].z; hv[3] = (_Float16)av[p].w;
                    *(half4*)&As[arb + p * 16][acol] = hv;
                }
            }
            {
                const _Float16* bp = bpB + k0 + bcc;
                half8 b0 = *(const half8*)(bp);
                half8 b1 = *(const half8*)(bp + 8);
                half8 b2 = *(const half8*)(bp + 16);
                half8 b3 = *(const half8*)(bp + 24);
                *(half8*)&Bs[bj][bcc]      = b0;
                *(half8*)&Bs[bj][bcc + 8]  = b1;
                *(half8*)&Bs[bj][bcc + 16] = b2;
                *(half8*)&Bs[bj][bcc + 24] = b3;
            }
            __syncthreads();
#pragma unroll
            for (int kss = 0; kss < 2; ++kss) {
                const int ko = kss * 32 + quad * 8;
                const half8 a0 = *(const half8*)&As[wave * 32 + m16][ko];
                const half8 a1 = *(const half8*)&As[wave * 32 + 16 + m16][ko];
#pragma unroll
                for (int c = 0; c < 4; ++c) {   // only cols < 64 exist
                    const half8 bf = *(const half8*)&Bs[c * 16 + m16][ko];
                    acc[0][c] = MFMA16(a0, bf, acc[0][c]);
                    acc[1][c] = MFMA16(a1, bf, acc[1][c]);
                }
            }
            __syncthreads();
        }

        // epilogue: vT[b][e][t] = (fp16)(acc + bv[e])
#pragma unroll
        for (int hh = 0; hh < 2; ++hh) {
#pragma unroll
            for (int c = 0; c < 4; ++c) {
                const int e  = c * 16 + m16;
                const float bb = bv[e];
#pragma unroll
                for (int r = 0; r < 4; ++r) {
                    const int row = m0 + wave * 32 + hh * 16 + quad * 4 + r;
                    const int b = row >> 10, tt = row & 1023;
                    vT[(long)b * 65536 + (long)e * 1024 + tt] =
                        (_Float16)(acc[hh][c][r] + bb);
                }
            }
        }
        return;
    }

    // ====== q+k projection role (double-buffer, counted vmcnt — R7) ======
    const int lid2 = lid - 32;            // 0..511
    const int xcd = lid2 & 7, loc = lid2 >> 3;
    const int sw  = xcd * 64 + loc;       // bijective (512 % 8 == 0)
    const int nt  = sw & 7;
    const int tm2 = sw >> 3;
    const int mt  = tm2 & 31;
    const int z   = tm2 >> 5;             // 0 = q, 1 = k

    const int n0 = nt * 128;
    const int m0 = mt * 128;

    const char* Az = (const char*)(A16 + (long)z * 4194304);
    const char* Bz = (const char*)(BT  + (long)z * 1048576);

    const int colbyte = (((lane & 7) ^ (lane >> 3)) << 4);
    const char* gaBase = Az + ((long)(m0 + wave * 32 + (lane >> 3)) << 11) + colbyte;
    const char* gbBase = Bz + ((long)(n0 + wave * 32 + (lane >> 3)) << 11) + colbyte;

    // LDS: As[2] at 0 / 16384; Bs[2] at 32768 / 49152 (each 128x64 fp16)
    f32x4 acc[2][8];
    {
        f32x4 zz = {0.f, 0.f, 0.f, 0.f};
#pragma unroll
        for (int i = 0; i < 2; ++i)
#pragma unroll
            for (int j = 0; j < 8; ++j) acc[i][j] = zz;
    }

    auto STAGE = [&](int bf, int k0) {
        const char* ga = gaBase + (k0 << 1);
        const char* gb = gbBase + (k0 << 1);
        _Float16* la = (_Float16*)(smem + bf * 16384) + wave * 32 * 64;
        _Float16* lb = (_Float16*)(smem + 32768 + bf * 16384) + wave * 32 * 64;
#pragma unroll
        for (int i = 0; i < 4; ++i) {
            glds16(ga + (long)i * 8 * 2048, la + i * 8 * 64);
            glds16(gb + (long)i * 8 * 2048, lb + i * 8 * 64);
        }
    };

    auto COMPUTE = [&](int bf) {
        const char* Ab = smem + bf * 16384;
        const char* Bp = smem + 32768 + bf * 16384;
        const int sw4 = (m16 & 7) << 4;
#pragma unroll
        for (int kss = 0; kss < 2; ++kss) {
            const int kbs = (kss * 64 + quad * 16) ^ sw4;
            const half8 a0 = *(const half8*)(Ab + (wave * 32 + m16) * 128 + kbs);
            const half8 a1 = *(const half8*)(Ab + (wave * 32 + 16 + m16) * 128 + kbs);
#pragma unroll
            for (int c = 0; c < 8; ++c) {
                const half8 bfr = *(const half8*)(Bp + (c * 16 + m16) * 128 + kbs);
                acc[0][c] = MFMA16(a0, bfr, acc[0][c]);
                acc[1][c] = MFMA16(a1, bfr, acc[1][c]);
            }
        }
    };

    STAGE(0, 0);
    STAGE(1, 64);                         // 16 glds in flight
    int cur = 0;
    for (int t = 0; t < 15; ++t) {
        asm volatile("s_waitcnt vmcnt(8)" ::: "memory");   // stage t landed
        __builtin_amdgcn_sched_barrier(0);
        BARRIER();
        COMPUTE(cur);
        BARRIER();
        if (t < 14) STAGE(cur, (t + 2) * 64);
        cur ^= 1;
    }
    asm volatile("s_waitcnt vmcnt(0)" ::: "memory");
    __builtin_amdgcn_sched_barrier(0);
    BARRIER();
    COMPUTE(cur);

    const float* bias = z ? bias1 : bias0;
    _Float16* Cz = Cout + (long)z * 4194304;
#pragma unroll
    for (int hh = 0; hh < 2; ++hh) {
#pragma unroll
        for (int c = 0; c < 8; ++c) {
            const int col = n0 + c * 16 + m16;
            const float bb = bias[col];
#pragma unroll
            for (int r = 0; r < 4; ++r) {
                const int row = m0 + wave * 32 + hh * 16 + quad * 4 + r;
                Cz[(long)row * 1024 + col] = (_Float16)(acc[hh][c][r] + bb);
            }
        }
    }
}

// ---------------------------------------------------------------------------
// MFMA GEMM (fp32 A path) — out-projection only.
// ---------------------------------------------------------------------------
__global__ __launch_bounds__(256, 2) void gemm_f16_v2(
    const float* __restrict__ A0, const float* __restrict__ A1,
    const _Float16* __restrict__ BT,
    const float* __restrict__ bias0, const float* __restrict__ bias1,
    void* __restrict__ Cout,
    int N, int lda, int ldbt, int ldc,
    long aBS, long bBS, long cBS,
    int c_half, int atomic, int nks, int kchunk)
{
    __shared__ __align__(16) _Float16 As[128][72];
    __shared__ __align__(16) _Float16 Bs[128][72];

    const int gx  = gridDim.x, gy = gridDim.y;
    const int nwg = gx * gy * (int)gridDim.z;
    const int lid = (int)blockIdx.x + gx * ((int)blockIdx.y + gy * (int)blockIdx.z);
    const int q8  = nwg >> 3, r8 = nwg & 7;
    const int xcd = lid & 7, loc = lid >> 3;
    const int sw  = (xcd < r8 ? xcd * (q8 + 1) : r8 * (q8 + 1) + (xcd - r8) * q8) + loc;
    const int nt  = sw % gx;
    const int tm2 = sw / gx;
    const int mt  = tm2 % gy;
    const int bz  = tm2 / gy;

    const int b = bz / nks, ks = bz % nks;
    const int kbeg = ks * kchunk;
    const int kend = kbeg + kchunk;

    const float* A = A1 ? (b ? A1 : A0) : (A0 + (long)b * aBS);
    const _Float16* Bb = BT + (long)b * bBS;

    const int n0 = nt * 128;
    const int m0 = mt * 128;
    const int tid  = threadIdx.x;
    const int wave = tid >> 6, lane = tid & 63;
    const int m16  = lane & 15, quad = lane >> 4;

    const int acol = (tid & 15) * 4;
    const int arb  = tid >> 4;
    const int bj   = tid >> 1;
    const int bcc  = (tid & 1) * 32;
    int jn = n0 + bj; if (jn > N - 1) jn = N - 1;
    const _Float16* bpB = Bb + (long)jn * ldbt;

    f32x4 acc[2][8];
    {
        f32x4 zz = {0.f, 0.f, 0.f, 0.f};
#pragma unroll
        for (int i = 0; i < 2; ++i)
#pragma unroll
            for (int j = 0; j < 8; ++j) acc[i][j] = zz;
    }

    for (int k0 = kbeg; k0 < kend; k0 += 64) {
        {
            float4 av[8];
#pragma unroll
            for (int p = 0; p < 8; ++p)
                av[p] = *(const float4*)(A + (long)(m0 + arb + p * 16) * lda + k0 + acol);
#pragma unroll
            for (int p = 0; p < 8; ++p) {
                half4 hv;
                hv[0] = (_Float16)av[p].x; hv[1] = (_Float16)av[p].y;
                hv[2] = (_Float16)av[p].z; hv[3] = (_Float16)av[p].w;
                *(half4*)&As[arb + p * 16][acol] = hv;
            }
        }
        {
            const _Float16* bp = bpB + k0 + bcc;
            half8 b0 = *(const half8*)(bp);
            half8 b1 = *(const half8*)(bp + 8);
            half8 b2 = *(const half8*)(bp + 16);
            half8 b3 = *(const half8*)(bp + 24);
            *(half8*)&Bs[bj][bcc]      = b0;
            *(half8*)&Bs[bj][bcc + 8]  = b1;
            *(half8*)&Bs[bj][bcc + 16] = b2;
            *(half8*)&Bs[bj][bcc + 24] = b3;
        }
        __syncthreads();
#pragma unroll
        for (int kss = 0; kss < 2; ++kss) {
            const int ko = kss * 32 + quad * 8;
            const half8 a0 = *(const half8*)&As[wave * 32 + m16][ko];
            const half8 a1 = *(const half8*)&As[wave * 32 + 16 + m16][ko];
#pragma unroll
            for (int c = 0; c < 8; ++c) {
                const half8 bf = *(const half8*)&Bs[c * 16 + m16][ko];
                acc[0][c] = MFMA16(a0, bf, acc[0][c]);
                acc[1][c] = MFMA16(a1, bf, acc[1][c]);
            }
        }
        __syncthreads();
    }

    const float* bias = b ? bias1 : bias0;
    const int addb = (bias != nullptr) && (kbeg == 0);
#pragma unroll
    for (int hh = 0; hh < 2; ++hh) {
#pragma unroll
        for (int c = 0; c < 8; ++c) {
            const int col = n0 + c * 16 + m16;
            if (col >= N) continue;
            const float bb = addb ? bias[col] : 0.f;
#pragma unroll
            for (int r = 0; r < 4; ++r) {
                const int row = m0 + wave * 32 + hh * 16 + quad * 4 + r;
                const float v = acc[hh][c][r] + bb;
                const long idx = (long)b * cBS + (long)row * ldc + col;
                if (atomic)      atomicAdd(&((float*)Cout)[idx], v);
                else if (c_half) ((_Float16*)Cout)[idx] = (_Float16)v;
                else             ((float*)Cout)[idx] = v;
            }
        }
    }
}

// ---------------------------------------------------------------------------
// Pass 1: per (b,h,s) row stats, KVBLK=128 (R6/R7-passing, unchanged).
// ---------------------------------------------------------------------------
__global__ __launch_bounds__(256, 4) void attn_stats(
    const _Float16* __restrict__ q_all, const _Float16* __restrict__ k_all,
    float* __restrict__ m_out, float* __restrict__ il_out)
{
    const int st = blockIdx.x, h = blockIdx.y, b = blockIdx.z;
    const int tid = threadIdx.x, wave = tid >> 6, lane = tid & 63;
    const int m16 = lane & 15, quad = lane >> 4;
    const int s0 = st * 64;
    const int sw = s0 + wave * 16;

    __shared__ __align__(16) _Float16 qs[64][72];
    __shared__ __align__(16) _Float16 ks[128][72];

    const int srow = tid >> 2;
    const int scol = (tid & 3) * 16;

    {
        const _Float16* qsrc = q_all + ((long)(b * 1024 + s0 + srow)) * 1024 + h * 64 + scol;
        *(half8*)&qs[srow][scol]     = *(const half8*)(qsrc);
        *(half8*)&qs[srow][scol + 8] = *(const half8*)(qsrc + 8);
    }

    const _Float16* ksrcb = k_all + ((long)(b * 1024 + srow)) * 1024 + h * 64 + scol;

    float mr[4], lr[4];
#pragma unroll
    for (int r = 0; r < 4; ++r) { mr[r] = -3.0e38f; lr[r] = 0.f; }

    half8 a0, a1;
    for (int ch = 0; 2 * ch <= st; ++ch) {
        const int tbase = 2 * ch;
        const int two = (tbase + 1 <= st);

        const _Float16* ksrc0 = ksrcb + (long)(tbase * 64) * 1024;
        const half8 k0 = *(const half8*)(ksrc0);
        const half8 k1 = *(const half8*)(ksrc0 + 8);
        half8 k2, k3;
        if (two) {
            const _Float16* ksrc1 = ksrc0 + (long)64 * 1024;
            k2 = *(const half8*)(ksrc1);
            k3 = *(const half8*)(ksrc1 + 8);
        }

        __syncthreads();
        *(half8*)&ks[srow][scol]     = k0;
        *(half8*)&ks[srow][scol + 8] = k1;
        if (two) {
            *(half8*)&ks[64 + srow][scol]     = k2;
            *(half8*)&ks[64 + srow][scol + 8] = k3;
        }
        __syncthreads();

        if (ch == 0) {
            a0 = *(const half8*)&qs[wave * 16 + m16][quad * 8];
            a1 = *(const half8*)&qs[wave * 16 + m16][quad * 8 + 32];
        }

        const int ncol = two ? 8 : 4;
        for (int c = 0; c < ncol; ++c) {
            const half8 b0 = *(const half8*)&ks[c * 16 + m16][quad * 8];
            const half8 b1 = *(const half8*)&ks[c * 16 + m16][quad * 8 + 32];
            f32x4 cc = {0.f, 0.f, 0.f, 0.f};
            cc = MFMA16(a0, b0, cc);
            cc = MFMA16(a1, b1, cc);
            const int tile = tbase + (c >> 2);
            if (tile < st) {
#pragma unroll
                for (int r = 0; r < 4; ++r) {
                    const float zz = cc[r] * 0.125f;
                    const float nm = fmaxf(mr[r], zz);
                    lr[r] = lr[r] * __expf(mr[r] - nm) + __expf(zz - nm);
                    mr[r] = nm;
                }
            } else {
                const int col = tile * 64 + (c & 3) * 16 + m16;
#pragma unroll
                for (int r = 0; r < 4; ++r) {
                    const int row = sw + quad * 4 + r;
                    if (col <= row) {
                        const float zz = cc[r] * 0.125f;
                        const float nm = fmaxf(mr[r], zz);
                        lr[r] = lr[r] * __expf(mr[r] - nm) + __expf(zz - nm);
                        mr[r] = nm;
                    }
                }
            }
        }
    }

#pragma unroll
    for (int mk = 1; mk < 16; mk <<= 1) {
#pragma unroll
        for (int r = 0; r < 4; ++r) {
            const float om = __shfl_xor(mr[r], mk);
            const float ol = __shfl_xor(lr[r], mk);
            const float nm = fmaxf(mr[r], om);
            lr[r] = lr[r] * __expf(mr[r] - nm) + ol * __expf(om - nm);
            mr[r] = nm;
        }
    }
    if (m16 == 0) {
#pragma unroll
        for (int r = 0; r < 4; ++r) {
            const long idx = ((long)(b * 16 + h)) * 1024 + sw + quad * 4 + r;
            m_out[idx]  = mr[r];
            il_out[idx] = 1.f / lr[r];
        }
    }
}

// ---------------------------------------------------------------------------
// Pass 2: head-mean softmax + fused PV. Trivial blocks write the attn
// upper-triangle zeros (overlap working blocks -> free).
// ---------------------------------------------------------------------------
__global__ __launch_bounds__(256, 4) void attn_pmean(
    const _Float16* __restrict__ q_all, const _Float16* __restrict__ k_all,
    const float* __restrict__ m_in, const float* __restrict__ il_in,
    const _Float16* __restrict__ vT,
    float* __restrict__ attn,
    float* __restrict__ ctx)
{
    const int ttile = blockIdx.x, stile = blockIdx.y, b = blockIdx.z;
    const int tid = threadIdx.x;
    if (ttile > stile) {
        const int c4 = (tid & 15) * 4;
        float4 zz = {0.f, 0.f, 0.f, 0.f};
#pragma unroll
        for (int i = 0; i < 4; ++i) {
            const int r = stile * 64 + (tid >> 4) + i * 16;
            *(float4*)&attn[((long)(b * 1024 + r)) * 1024 + ttile * 64 + c4] = zz;
        }
        return;
    }

    __shared__ __align__(16) _Float16 qs2[2][64 * 64];
    __shared__ __align__(16) _Float16 ks2[2][64 * 64];
    __shared__ __align__(16) float mls[16][64];
    __shared__ __align__(16) float ils[16][64];

    const int wave = tid >> 6, lane = tid & 63;
    const int m16 = lane & 15, quad = lane >> 4;
    const int s0 = stile * 64;
    const int t0 = ttile * 64;
    const int sw = s0 + wave * 16;
    const int diag = (ttile == stile);

    {
        const int hh = tid >> 4;
        const int c4 = (tid & 15) * 4;
        const long ix = ((long)(b * 16 + hh)) * 1024 + s0 + c4;
        const float4 mv4 = *(const float4*)&m_in[ix];
        const float4 iv4 = *(const float4*)&il_in[ix];
        *(float4*)&mls[hh][c4] = mv4;
        *(float4*)&ils[hh][c4] = iv4;
    }

    const int colb = (((lane & 7) ^ (lane >> 3)) << 4);
    const char* gq = (const char*)q_all + ((long)(b * 1024 + s0 + wave * 16 + (lane >> 3)) << 11) + colb;
    const char* gk = (const char*)k_all + ((long)(b * 1024 + t0 + wave * 16 + (lane >> 3)) << 11) + colb;

    auto STAGE_P = [&](int bf, int h) {
        const char* q = gq + h * 128;
        const char* k = gk + h * 128;
        _Float16* lq = &qs2[bf][wave * 16 * 64];
        _Float16* lk = &ks2[bf][wave * 16 * 64];
        glds16(q, lq);
        glds16(q + 8 * 2048, lq + 8 * 64);
        glds16(k, lk);
        glds16(k + 8 * 2048, lk + 8 * 64);
    };

    STAGE_P(0, 0);
    STAGE_P(1, 1);
    asm volatile("s_waitcnt lgkmcnt(0)" ::: "memory");
    BARRIER();

    float pm[4][4];
#pragma unroll
    for (int c = 0; c < 4; ++c)
#pragma unroll
        for (int r = 0; r < 4; ++r) pm[c][r] = 0.f;

    const int swz = (m16 & 7) << 4;
    int cur = 0;

    auto COMPUTE_H = [&](int h, int bf) {
        const char* Qc = (const char*)&qs2[bf][0];
        const char* Kc = (const char*)&ks2[bf][0];
        const half8 a0 = *(const half8*)(Qc + (wave * 16 + m16) * 128 + ((quad * 16) ^ swz));
        const half8 a1 = *(const half8*)(Qc + (wave * 16 + m16) * 128 + ((quad * 16 + 64) ^ swz));
        const float4 mv = *(const float4*)&mls[h][wave * 16 + quad * 4];
        const float4 iv = *(const float4*)&ils[h][wave * 16 + quad * 4];
        const float mrow[4] = {mv.x, mv.y, mv.z, mv.w};
        const float irow[4] = {iv.x, iv.y, iv.z, iv.w};
        if (!diag) {
#pragma unroll
            for (int c = 0; c < 4; ++c) {
                const half8 b0 = *(const half8*)(Kc + (c * 16 + m16) * 128 + ((quad * 16) ^ swz));
                const half8 b1 = *(const half8*)(Kc + (c * 16 + m16) * 128 + ((quad * 16 + 64) ^ swz));
                f32x4 cc = {0.f, 0.f, 0.f, 0.f};
                cc = MFMA16(a0, b0, cc);
                cc = MFMA16(a1, b1, cc);
#pragma unroll
                for (int r = 0; r < 4; ++r)
                    pm[c][r] += __expf(cc[r] * 0.125f - mrow[r]) * irow[r];
            }
        } else {
#pragma unroll
            for (int c = 0; c < 4; ++c) {
                const half8 b0 = *(const half8*)(Kc + (c * 16 + m16) * 128 + ((quad * 16) ^ swz));
                const half8 b1 = *(const half8*)(Kc + (c * 16 + m16) * 128 + ((quad * 16 + 64) ^ swz));
                f32x4 cc = {0.f, 0.f, 0.f, 0.f};
                cc = MFMA16(a0, b0, cc);
                cc = MFMA16(a1, b1, cc);
                const int col = t0 + c * 16 + m16;
#pragma unroll
                for (int r = 0; r < 4; ++r) {
                    const int row = sw + quad * 4 + r;
                    if (col <= row)
                        pm[c][r] += __expf(cc[r] * 0.125f - mrow[r]) * irow[r];
                }
            }
        }
    };

    for (int h = 0; h < 15; ++h) {
        asm volatile("s_waitcnt vmcnt(4)" ::: "memory");
        __builtin_amdgcn_sched_barrier(0);
        BARRIER();
        COMPUTE_H(h, cur);
        BARRIER();
        if (h < 14) STAGE_P(cur, h + 2);
        cur ^= 1;
    }
    asm volatile("s_waitcnt vmcnt(0)" ::: "memory");
    __builtin_amdgcn_sched_barrier(0);
    BARRIER();
    COMPUTE_H(15, cur);
    __syncthreads();   // all waves done reading LDS; qs2[0] reusable for P

    // attn write + P stash into qs2[0], chunk-XOR swizzled
    {
        char* Pb = (char*)&qs2[0][0];
#pragma unroll
        for (int c = 0; c < 4; ++c) {
#pragma unroll
            for (int r = 0; r < 4; ++r) {
                const int rloc = (wave << 4) + (quad << 2) + r;
                const int cloc = c * 16 + m16;
                const float p = pm[c][r] * 0.0625f;
                attn[((long)(b * 1024 + s0 + rloc)) * 1024 + t0 + cloc] = p;
                const int chunk = (cloc >> 3) ^ (rloc & 7);
                *(_Float16*)(Pb + rloc * 128 + (chunk << 4) + (cloc & 7) * 2) =
                    (_Float16)p;
            }
        }
    }
    __syncthreads();

    // PV: ctx[s][e] += sum_t P[s][t] * vT[e][t]
    const _Float16* vTb = vT + (long)b * 65536 + t0;
    const char* Pb = (const char*)&qs2[0][0];
    const int Rr = wave * 16 + m16;
    f32x4 apv[4];
    {
        f32x4 zz = {0.f, 0.f, 0.f, 0.f};
#pragma unroll
        for (int c = 0; c < 4; ++c) apv[c] = zz;
    }
#pragma unroll
    for (int kss = 0; kss < 2; ++kss) {
        const int chunk = (kss * 4 + quad) ^ (Rr & 7);
        const half8 a = *(const half8*)(Pb + Rr * 128 + (chunk << 4));
#pragma unroll
        for (int c = 0; c < 4; ++c) {
            const half8 bf = *(const half8*)(vTb + (long)(c * 16 + m16) * 1024 + kss * 32 + quad * 8);
            apv[c] = MFMA16(a, bf, apv[c]);
        }
    }
#pragma unroll
    for (int c = 0; c < 4; ++c) {
#pragma unroll
        for (int r = 0; r < 4; ++r) {
            const int row = sw + quad * 4 + r;
            const int e   = c * 16 + m16;
            atomicAdd(&ctx[((long)(b * 1024 + row)) * 64 + e], apv[c][r]);
        }
    }
}

// ---------------------------------------------------------------------------
extern "C" void kernel_launch(void* const* d_in, const int* in_sizes, int n_in,
                              void* d_out, int out_size, void* d_ws, size_t ws_size,
                              hipStream_t stream)
{
    const float* queries = (const float*)d_in[0];
    const float* keys    = (const float*)d_in[1];
    const float* values  = (const float*)d_in[2];
    const float* Wq = (const float*)d_in[4];
    const float* bq = (const float*)d_in[5];
    const float* Wk = (const float*)d_in[6];
    const float* bk = (const float*)d_in[7];
    const float* Wv = (const float*)d_in[8];
    const float* bv = (const float*)d_in[9];
    const float* Wo = (const float*)d_in[10];
    const float* bo = (const float*)d_in[11];

    float* out_ptr  = (float*)d_out;                   // [4096][1024]
    float* attn_ptr = out_ptr + (long)4096 * 1024;     // [4][1024][1024]

    uint8_t* w = (uint8_t*)d_ws;
    size_t off = 0;
    auto alloc = [&](size_t bytes) {
        void* p = w + off;
        off = (off + bytes + 255) & ~(size_t)255;
        return p;
    };
    _Float16* WqkT  = (_Float16*)alloc((size_t)2 * 1024 * 1024 * 2); // WqT|WkT
    _Float16* WvT   = (_Float16*)alloc((size_t)64 * 1024 * 2);       // [e][d]
    _Float16* WoT   = (_Float16*)alloc((size_t)1024 * 64 * 2);       // [d][e]
    _Float16* qkall = (_Float16*)alloc((size_t)2 * 4194304 * 2);     // qall|kall
    _Float16* a16   = (_Float16*)alloc((size_t)2 * 4194304 * 2);     // q16|k16
    _Float16* vT    = (_Float16*)alloc((size_t)4 * 64 * 1024 * 2);   // per-b [e][t]
    float*    ctx   = (float*)alloc((size_t)4096 * 64 * 4);
    float*    mbuf  = (float*)alloc((size_t)65536 * 4);
    float*    ilbuf = (float*)alloc((size_t)65536 * 4);
    (void)ws_size; (void)in_sizes; (void)n_in; (void)out_size;

    _Float16* qall = qkall;
    _Float16* kall = qkall + (long)4194304;

    // 1. prep: transposes + cvt + zero ctx
    prep_all<<<dim3(6528, 1, 1), 256, 0, stream>>>(
        Wq, Wk, Wv, Wo, queries, keys,
        WqkT, WvT, WoT, a16, ctx);

    // 2. fused q+k projection (512 blocks, dbuf) + v projection -> vT (32)
    qk_vproj<<<dim3(544, 1, 1), 256, 0, stream>>>(
        a16, WqkT, bq, bk, qkall, values, WvT, bv, vT);

    // 3. softmax stats (KVBLK=128)
    attn_stats<<<dim3(16, 16, 4), 256, 0, stream>>>(qall, kall, mbuf, ilbuf);

    // 4. head-mean probabilities + fused PV into ctx (+ upper-tri zeros)
    attn_pmean<<<dim3(16, 16, 4), 256, 0, stream>>>(qall, kall, mbuf, ilbuf, vT, attn_ptr, ctx);

    // 5. out = ctx @ Wo + bo
    gemm_f16_v2<<<dim3(8, 32, 1), 256, 0, stream>>>(
        ctx, nullptr, WoT, bo, nullptr, out_ptr,
        1024, 64, 64, 1024,
        0, 0, 0,
        /*c_half=*/0, /*atomic=*/0, /*nks=*/1, /*kchunk=*/64);
}